// Round 1
// baseline (88.210 us; speedup 1.0000x reference)
//
#include <hip/hip_runtime.h>
#include <hip/hip_bf16.h>
#include <math.h>

// HierarchicalAttention: softmax_j(score_p[i]+score_c[j]+b) — the i-dependent
// term cancels in the softmax, so out[i,:] = softmax(score_c) @ child for all i.
// Pipeline: K1 partial softmax-weighted sums -> K2 combine -> K3 broadcast.

#define HID 64          // hidden dim (hard requirement of this problem)
#define K1_BLOCKS 256   // chunks over C
#define CHUNK 64        // rows per K1 block (C=16384 -> exactly 64)
#define PARTIAL_STRIDE 66  // [m_b, s_b, vec_b[64]]

__global__ __launch_bounds__(256)
void ha_k1_partials(const float* __restrict__ child,
                    const float* __restrict__ attn_w,
                    float* __restrict__ partials, int C) {
    __shared__ float s_scores[CHUNK];
    __shared__ float s_vec[4][HID];

    const int lane = threadIdx.x & 63;
    const int wave = threadIdx.x >> 6;
    const int row0 = blockIdx.x * CHUNK;
    const int rows = min(CHUNK, C - row0);

    const float wc = attn_w[HID + lane];   // w_c[lane]

    // pass 1: score_c for this chunk; one wave per row, lane=feature
    for (int r = wave; r < rows; r += 4) {
        float p = child[(size_t)(row0 + r) * HID + lane] * wc;
        #pragma unroll
        for (int off = 32; off > 0; off >>= 1) p += __shfl_down(p, off);
        if (lane == 0) s_scores[r] = p;
    }
    __syncthreads();

    // chunk max + exp (each wave redundantly over the 64 scores)
    float sc = (lane < rows) ? s_scores[lane] : -INFINITY;
    float m = sc;
    #pragma unroll
    for (int off = 32; off > 0; off >>= 1) m = fmaxf(m, __shfl_down(m, off));
    m = __shfl(m, 0);
    float e = (lane < rows) ? expf(sc - m) : 0.0f;
    float ssum = e;
    #pragma unroll
    for (int off = 32; off > 0; off >>= 1) ssum += __shfl_down(ssum, off);
    ssum = __shfl(ssum, 0);
    __syncthreads();
    s_scores[lane] = e;   // all waves write identical values
    __syncthreads();

    // pass 2: vec_b[h] = sum_j e_j * child[j][h]  (rows L2-hot from pass 1)
    float acc = 0.0f;
    for (int r = wave; r < rows; r += 4)
        acc += s_scores[r] * child[(size_t)(row0 + r) * HID + lane];
    s_vec[wave][lane] = acc;
    __syncthreads();

    if (wave == 0) {
        float tot = s_vec[0][lane] + s_vec[1][lane] + s_vec[2][lane] + s_vec[3][lane];
        float* p = partials + (size_t)blockIdx.x * PARTIAL_STRIDE;
        if (lane == 0) { p[0] = m; p[1] = ssum; }
        p[2 + lane] = tot;
    }
}

__global__ __launch_bounds__(64)
void ha_k2_combine(const float* __restrict__ partials, float* __restrict__ outvec) {
    const int lane = threadIdx.x;   // 64 threads, 1 wave
    // global max over block maxima
    float m = -INFINITY;
    for (int b = lane; b < K1_BLOCKS; b += 64)
        m = fmaxf(m, partials[(size_t)b * PARTIAL_STRIDE]);
    #pragma unroll
    for (int off = 32; off > 0; off >>= 1) m = fmaxf(m, __shfl_down(m, off));
    m = __shfl(m, 0);

    float s = 0.0f, v = 0.0f;
    for (int b = 0; b < K1_BLOCKS; ++b) {
        const float* p = partials + (size_t)b * PARTIAL_STRIDE;
        float scale = expf(p[0] - m);   // scalar loads broadcast across the wave
        s += p[1] * scale;
        v += p[2 + lane] * scale;
    }
    outvec[lane] = v / s;
}

__global__ __launch_bounds__(256)
void ha_k3_broadcast(const float* __restrict__ outvec, float4* __restrict__ out, int n4) {
    int t = blockIdx.x * 256 + threadIdx.x;
    if (t < n4) {
        const float4* v4 = (const float4*)outvec;
        out[t] = v4[t & 15];   // column float4-index: H=64 -> 16 float4 per row
    }
}

extern "C" void kernel_launch(void* const* d_in, const int* in_sizes, int n_in,
                              void* d_out, int out_size, void* d_ws, size_t ws_size,
                              hipStream_t stream) {
    const float* child  = (const float*)d_in[1];   // (C, 64)
    const float* attn_w = (const float*)d_in[2];   // (1, 128)
    const int C = in_sizes[1] / HID;               // 16384

    float* partials = (float*)d_ws;                            // 256*66 floats
    float* outvec   = partials + (size_t)K1_BLOCKS * PARTIAL_STRIDE; // 64 floats

    ha_k1_partials<<<K1_BLOCKS, 256, 0, stream>>>(child, attn_w, partials, C);
    ha_k2_combine<<<1, 64, 0, stream>>>(partials, outvec);

    const int n4 = out_size / 4;                   // 131072 float4
    ha_k3_broadcast<<<(n4 + 255) / 256, 256, 0, stream>>>(outvec, (float4*)d_out, n4);
}

// Round 2
// 75.716 us; speedup vs baseline: 1.1650x; 1.1650x over previous
//
#include <hip/hip_runtime.h>
#include <hip/hip_bf16.h>
#include <math.h>

// HierarchicalAttention: softmax_j(score_p[i]+score_c[j]+b) — the i-dependent
// term cancels inside the softmax, so out[i,:] = softmax(score_c) @ child for
// every i. Two kernels:
//   K1 (256 blocks): per-64-row chunk -> (max, expsum, weighted vec) partial.
//   K2 (512 blocks): every block redundantly combines the 256 partials
//                    (logsumexp, parallel across 4 waves, L2-hot) and writes
//                    its 16-row slice of the broadcast output.

#define HID 64             // hidden dim
#define K1_BLOCKS 256      // chunks over C (C=16384 -> 64 rows each)
#define CHUNK 64
#define PARTIAL_STRIDE 66  // [m_b, s_b, vec_b[64]]
#define K2_BLOCKS 512

__global__ __launch_bounds__(256)
void ha_k1_partials(const float* __restrict__ child,
                    const float* __restrict__ attn_w,
                    float* __restrict__ partials, int C) {
    __shared__ float s_child[CHUNK][HID];   // 16 KB stage (2-way LDS alias = free)
    __shared__ float s_scores[CHUNK];
    __shared__ float s_vec[4][HID];

    const int lane = threadIdx.x & 63;
    const int wave = threadIdx.x >> 6;
    const int row0 = blockIdx.x * CHUNK;
    const int rows = min(CHUNK, C - row0);

    const float wc = attn_w[HID + lane];    // w_c[lane]

    // pass 1: stage rows in LDS + score_c; one wave per row, lane = feature
    for (int r = wave; r < rows; r += 4) {
        float x = child[(size_t)(row0 + r) * HID + lane];
        s_child[r][lane] = x;
        float p = x * wc;
        #pragma unroll
        for (int off = 32; off > 0; off >>= 1) p += __shfl_down(p, off);
        if (lane == 0) s_scores[r] = p;
    }
    __syncthreads();

    // chunk max + exp (each wave redundantly over the 64 scores)
    float sc = (lane < rows) ? s_scores[lane] : -INFINITY;
    float m = sc;
    #pragma unroll
    for (int off = 32; off > 0; off >>= 1) m = fmaxf(m, __shfl_down(m, off));
    m = __shfl(m, 0);
    float e = (lane < rows) ? expf(sc - m) : 0.0f;
    float ssum = e;
    #pragma unroll
    for (int off = 32; off > 0; off >>= 1) ssum += __shfl_down(ssum, off);
    ssum = __shfl(ssum, 0);
    __syncthreads();
    s_scores[lane] = e;                     // all waves write identical values
    __syncthreads();

    // pass 2: vec_b[h] = sum_j e_j * child[j][h]  (from LDS)
    float acc = 0.0f;
    for (int r = wave; r < rows; r += 4)
        acc += s_scores[r] * s_child[r][lane];
    s_vec[wave][lane] = acc;
    __syncthreads();

    if (wave == 0) {
        float tot = s_vec[0][lane] + s_vec[1][lane] + s_vec[2][lane] + s_vec[3][lane];
        float* p = partials + (size_t)blockIdx.x * PARTIAL_STRIDE;
        if (lane == 0) { p[0] = m; p[1] = ssum; }
        p[2 + lane] = tot;
    }
}

__global__ __launch_bounds__(256)
void ha_k2_combine_bcast(const float* __restrict__ partials,
                         float4* __restrict__ out, int n4) {
    __shared__ float s_wm[4];
    __shared__ float s_ws[4];
    __shared__ float s_scale[K1_BLOCKS];
    __shared__ float s_v[4][HID];
    __shared__ float s_out[HID];

    const int t = threadIdx.x;
    const int lane = t & 63;
    const int wave = t >> 6;

    // each of the 256 threads owns one partial's (m_b, s_b)
    const float* pb = partials + (size_t)t * PARTIAL_STRIDE;
    const float mb = pb[0];
    const float sb = pb[1];

    // global max over 256 block maxima
    float m = mb;
    #pragma unroll
    for (int off = 32; off > 0; off >>= 1) m = fmaxf(m, __shfl_down(m, off));
    if (lane == 0) s_wm[wave] = m;
    __syncthreads();
    m = fmaxf(fmaxf(s_wm[0], s_wm[1]), fmaxf(s_wm[2], s_wm[3]));

    // per-partial rescale + total expsum
    const float scale = expf(mb - m);
    s_scale[t] = scale;
    float ss = sb * scale;
    #pragma unroll
    for (int off = 32; off > 0; off >>= 1) ss += __shfl_down(ss, off);
    if (lane == 0) s_ws[wave] = ss;
    __syncthreads();
    const float stot = s_ws[0] + s_ws[1] + s_ws[2] + s_ws[3];

    // combine vectors: wave w sums partials [w*64, w*64+64), lane = feature
    float v = 0.0f;
    const float* base = partials + (size_t)(wave * 64) * PARTIAL_STRIDE + 2 + lane;
    #pragma unroll 8
    for (int i = 0; i < 64; ++i)
        v += base[(size_t)i * PARTIAL_STRIDE] * s_scale[wave * 64 + i];
    s_v[wave][lane] = v;
    __syncthreads();

    if (t < HID)
        s_out[t] = (s_v[0][t] + s_v[1][t] + s_v[2][t] + s_v[3][t]) / stot;
    __syncthreads();

    // broadcast this block's slice of the output
    const float4* v4 = (const float4*)s_out;
    for (int idx = blockIdx.x * 256 + t; idx < n4; idx += K2_BLOCKS * 256)
        out[idx] = v4[idx & 15];   // H=64 -> 16 float4 per row
}

extern "C" void kernel_launch(void* const* d_in, const int* in_sizes, int n_in,
                              void* d_out, int out_size, void* d_ws, size_t ws_size,
                              hipStream_t stream) {
    const float* child  = (const float*)d_in[1];   // (C, 64)
    const float* attn_w = (const float*)d_in[2];   // (1, 128)
    const int C = in_sizes[1] / HID;               // 16384

    float* partials = (float*)d_ws;                // 256*66 floats

    ha_k1_partials<<<K1_BLOCKS, 256, 0, stream>>>(child, attn_w, partials, C);

    const int n4 = out_size / 4;                   // 131072 float4
    ha_k2_combine_bcast<<<K2_BLOCKS, 256, 0, stream>>>(partials, (float4*)d_out, n4);
}